// Round 13
// baseline (428.988 us; speedup 1.0000x reference)
//
#include <hip/hip_runtime.h>

// WeatherLSTM on MI355X — round 13: serial-tail bundle.
// 256 wgs x 512 threads; each wg owns 8 batch rows for all 279 steps.
// Per step: M=16(8 used),N=768,K=288 bf16 MFMA; f-gate dropped; x folded
// as 9th K-tile; bias via constant-1.0 A slot; A-row duplication (c&7);
// h in exact A-fragment layout (conflict-free, proven r12).
// B: 28 VGPR-born + 8 AGPR-born + 18 LDS per wave (proven stable).
// NEW: (1) phase order i->g->o with t2=tanh(ii*gg) computed UNDER the
// o-phase MFMAs -> post-MFMA tail is just sigm(o)+mul+pack+write;
// (2) i,o weights packed with -log2e (sigm needs no negate);
// (3) y-output barrier-free: wave 0 reads the published buffer at the top
// of the NEXT step (stable), shfl-reduce, direct store — the 2 extra
// barriers on 24 decode steps are gone; (4) x-prefetch on wave 7.

typedef short bf16x8 __attribute__((ext_vector_type(8)));
typedef float f32x4 __attribute__((ext_vector_type(4)));

#define T_ENC 256
#define N_DEC 23
#define NSTEP 279
#define PV_T 28            // B-tiles born in arch VGPRs
#define PA_T 8             // B-tiles born in AGPRs
#define LDS_T 18           // B-tiles per wave in LDS (g gate)
#define AFRAG 2304         // 9 kt * 4 q * 8 row * 8 e shorts

__device__ __forceinline__ short f2bf(float f) {
  unsigned u = __float_as_uint(f);
  u = (u + 0x7fffu + ((u >> 16) & 1u)) >> 16;  // RNE
  return (short)u;
}
__device__ __forceinline__ float bf2f(short s) {
  return __uint_as_float(((unsigned)(unsigned short)s) << 16);
}

#if __has_builtin(__builtin_amdgcn_rcpf)
#define RCPF(x) __builtin_amdgcn_rcpf(x)
#else
#define RCPF(x) (1.0f / (x))
#endif
#if __has_builtin(__builtin_amdgcn_exp2f)
#define EXP2(x) __builtin_amdgcn_exp2f(x)
#else
#define EXP2(x) __exp2f(x)
#endif

// Pack [Wh;Wx;bias;0] (3 gates i|o|g) into B-frag layout, exp2 domain:
// i,o rows x (-log2e)  -> sigm = rcp(1+2^acc);
// g  rows x (2*log2e)  -> tanh = 1-2*rcp(2^acc+1).
__global__ void pack_kernel(const float* __restrict__ Wx, const float* __restrict__ Wh,
                            const float* __restrict__ b, short* __restrict__ Wpack) {
  int tau = blockIdx.x;  // 0..431 = n_tile*9 + kt
  int l = threadIdx.x;
  int n_tile = tau / 9, kt = tau % 9;
  int w = n_tile / 6, t = n_tile % 6;
  int gate = t >> 1, loc = t & 1;
  int base = (gate == 0) ? 0 : (gate == 1 ? 512 : 768);  // [i|f|o|c], f dropped
  float scale = (gate == 2) ? 2.885390082f : -1.442695041f;
  int c = l & 15, q = l >> 4;
  int oc = base + w * 32 + loc * 16 + c;
  bf16x8 v;
#pragma unroll
  for (int e = 0; e < 8; ++e) {
    int k = kt * 32 + q * 8 + e;
    float f;
    if (k < 256)       f = Wh[k * 1024 + oc];
    else if (k < 264)  f = Wx[(k - 256) * 1024 + oc];
    else if (k == 264) f = b[oc];
    else               f = 0.0f;
    v[e] = f2bf(f * scale);
  }
  ((bf16x8*)Wpack)[tau * 64 + l] = v;
}

__global__ __launch_bounds__(512, 2) void lstm_kernel(
    const float* __restrict__ inputs0, const float* __restrict__ inputs1,
    const float* __restrict__ Wy, const float* __restrict__ by,
    const float* __restrict__ dec_w, const float* __restrict__ dec_b,
    const short* __restrict__ Wpack, float* __restrict__ out) {
  __shared__ __align__(16) short B_lds[8 * LDS_T * 512];  // 147456 B
  __shared__ __align__(16) short A_lds[2][AFRAG];         // 9216 B, double-buffered
  __shared__ float Wy_lds[256];
  // total ~157.7 KB -> exactly 1 wg/CU

  const int tid = threadIdx.x;
  const int wg = blockIdx.x;     // 0..255, batch rows wg*8 .. wg*8+7
  const int lane = tid & 63;
  const int w = tid >> 6;        // wave 0..7
  const int q = lane >> 4;       // 0..3
  const int c = lane & 15;

  const bf16x8* wp = (const bf16x8*)Wpack;

  // ---- B residency: 28 VGPR-born + 8 AGPR-born + 18 LDS ----
  bf16x8 Bv[PV_T];
#pragma unroll
  for (int r = 0; r < PV_T; ++r) {
    bf16x8 t0 = wp[(w * 54 + r) * 64 + lane];
    asm("" : "=v"(Bv[r]) : "0"(t0));
  }
  bf16x8 Ba[PA_T];
#pragma unroll
  for (int r = 0; r < PA_T; ++r) {
    bf16x8 t0 = wp[(w * 54 + PV_T + r) * 64 + lane];
    asm("" : "=a"(Ba[r]) : "0"(t0));
  }
#pragma unroll
  for (int j = 0; j < LDS_T; ++j) {
    bf16x8 v = wp[(w * 54 + PV_T + PA_T + j) * 64 + lane];
    *(bf16x8*)(B_lds + (w * LDS_T + j) * 512 + lane * 8) = v;
  }

  for (int i = tid; i < 2 * AFRAG; i += 512) A_lds[0][i] = 0;
  if (tid < 256) Wy_lds[tid] = Wy[tid];
  __syncthreads();  // zero-init complete before x0/bias staging

  if (tid < 64)  // stage x(step 0): frag region kt=8,q=0
    A_lds[0][2048 + tid] = f2bf(inputs0[((wg * 8 + (tid >> 3)) * 256 + 0) * 8 + (tid & 7)]);
  if (tid < 16)  // constant 1.0 at k=264 (kt=8,q=1,e=0) in BOTH buffers
    A_lds[tid >> 3][2112 + (tid & 7) * 8] = (short)0x3F80;
  const float byv = by[0];
  __syncthreads();

#define LDSB(j) (*(const bf16x8*)(B_lds + (w * LDS_T + (j)) * 512 + lane * 8))

  const int qh = q >> 1;
  const int row0 = (q & 1) * 4;
  const int woff = w * 256 + (qh * 2 + (c >> 3)) * 64 + row0 * 8 + (c & 7);
  const int abase = q * 64 + (c & 7) * 8;  // A-read base (shorts)

  f32x4 z4;
  z4[0] = 0.f; z4[1] = 0.f; z4[2] = 0.f; z4[3] = 0.f;
  asm("" : "+v"(z4));  // materialized once

  for (int s = 0; s < NSTEP; ++s) {
    const short* Ab = &A_lds[s & 1][0];
    short* An = &A_lds[(s + 1) & 1][0];

    // barrier-free y: wave 0 computes y-col (s-256) from the published
    // read-buffer (stable all step). Covers cols 0..22; col 23 post-loop.
    if (w == 0 && s >= 256) {
      int m = lane >> 3, c8 = lane & 7;
      const short* hp = Ab + c8 * 256 + m * 8;
      float part = 0.0f;
#pragma unroll
      for (int qq = 0; qq < 4; ++qq) {
        bf16x8 hv = *(const bf16x8*)(hp + qq * 64);
#pragma unroll
        for (int e = 0; e < 8; ++e)
          part += bf2f(hv[e]) * Wy_lds[c8 * 32 + qq * 8 + e];
      }
      part += __shfl_xor(part, 1);
      part += __shfl_xor(part, 2);
      part += __shfl_xor(part, 4);
      if (c8 == 0) out[(wg * 8 + m) * 24 + (s - 256)] = part + byv;
    }

    // x prefetch for s+1 on wave 7 (wave 0 is busy with y on decode steps)
    float xv = 0.0f;
    const bool do_x = (tid >= 448) && (s + 1 < NSTEP);
    const int xl = tid - 448;
    if (do_x) {
      int sn = s + 1, xm = xl >> 3, xk = xl & 7;
      if (sn < T_ENC) {
        xv = inputs0[((wg * 8 + xm) * 256 + sn) * 8 + xk];
      } else {
        int d = sn - T_ENC;
        xv = inputs1[(wg * 8 + xm) * N_DEC + d] * dec_w[d * 8 + xk] + dec_b[d * 8 + xk];
      }
    }

    // A-fragments: 1 base + imm offsets, contiguous, conflict-free
    bf16x8 A[9];
#pragma unroll
    for (int kt = 0; kt < 9; ++kt)
      A[kt] = *(const bf16x8*)(Ab + kt * 256 + abase);

    // ---- phase i (t=0,1): Bv[0..17] ----
    __builtin_amdgcn_s_setprio(1);
    f32x4 a0 = __builtin_amdgcn_mfma_f32_16x16x32_bf16(A[0], Bv[0], z4, 0, 0, 0);
    f32x4 a1 = __builtin_amdgcn_mfma_f32_16x16x32_bf16(A[0], Bv[9], z4, 0, 0, 0);
#pragma unroll
    for (int kt = 1; kt < 9; ++kt) {
      a0 = __builtin_amdgcn_mfma_f32_16x16x32_bf16(A[kt], Bv[kt], a0, 0, 0, 0);
      a1 = __builtin_amdgcn_mfma_f32_16x16x32_bf16(A[kt], Bv[9 + kt], a1, 0, 0, 0);
    }
    __builtin_amdgcn_s_setprio(0);
    float ii[4];
    {
      const f32x4 vi = qh ? a1 : a0;
#pragma unroll
      for (int j = 0; j < 4; ++j) ii[j] = RCPF(1.0f + EXP2(vi[j]));  // -log2e folded
    }

    // ---- phase g (t=4,5): B from LDS ----
    __builtin_amdgcn_s_setprio(1);
    a0 = __builtin_amdgcn_mfma_f32_16x16x32_bf16(A[0], LDSB(0), z4, 0, 0, 0);
    a1 = __builtin_amdgcn_mfma_f32_16x16x32_bf16(A[0], LDSB(9), z4, 0, 0, 0);
#pragma unroll
    for (int kt = 1; kt < 9; ++kt) {
      a0 = __builtin_amdgcn_mfma_f32_16x16x32_bf16(A[kt], LDSB(kt), a0, 0, 0, 0);
      a1 = __builtin_amdgcn_mfma_f32_16x16x32_bf16(A[kt], LDSB(9 + kt), a1, 0, 0, 0);
    }
    __builtin_amdgcn_s_setprio(0);
    float t2[4];
    {
      const f32x4 vg = qh ? a1 : a0;
#pragma unroll
      for (int j = 0; j < 4; ++j) {
        float gg = 1.0f - 2.0f * RCPF(EXP2(vg[j]) + 1.0f);   // tanh(g)
        float cy = ii[j] * gg;
        t2[j] = 1.0f - 2.0f * RCPF(EXP2(cy * 2.885390082f) + 1.0f);  // tanh(cy)
      }
    }

    // ---- phase o (t=2,3): Bv[18..27]+Ba — t2 computes under these MFMAs ----
    __builtin_amdgcn_s_setprio(1);
    a0 = __builtin_amdgcn_mfma_f32_16x16x32_bf16(A[0], Bv[18], z4, 0, 0, 0);
    a1 = __builtin_amdgcn_mfma_f32_16x16x32_bf16(A[0], Bv[27], z4, 0, 0, 0);
#pragma unroll
    for (int kt = 1; kt < 9; ++kt) {
      a0 = __builtin_amdgcn_mfma_f32_16x16x32_bf16(A[kt], Bv[18 + kt], a0, 0, 0, 0);
      a1 = __builtin_amdgcn_mfma_f32_16x16x32_bf16(A[kt], Ba[kt - 1], a1, 0, 0, 0);
    }
    __builtin_amdgcn_s_setprio(0);
    // short tail: sigm(o), combine, pack, write
    {
      const f32x4 vo = qh ? a1 : a0;
      float hh[4];
#pragma unroll
      for (int j = 0; j < 4; ++j)
        hh[j] = RCPF(1.0f + EXP2(vo[j])) * t2[j];
      unsigned pk01, pk23;
      asm("v_cvt_pk_bf16_f32 %0, %1, %2" : "=v"(pk01) : "v"(hh[0]), "v"(hh[1]));
      asm("v_cvt_pk_bf16_f32 %0, %1, %2" : "=v"(pk23) : "v"(hh[2]), "v"(hh[3]));
      An[woff + 0 * 8] = (short)(pk01 & 0xffffu);
      An[woff + 1 * 8] = (short)(pk01 >> 16);
      An[woff + 2 * 8] = (short)(pk23 & 0xffffu);
      An[woff + 3 * 8] = (short)(pk23 >> 16);
    }
    if (do_x) An[2048 + xl] = f2bf(xv);
    __syncthreads();  // the ONLY barrier: publish h(s+1)
  }

  // final y-col 23 from the last published buffer (loop barrier suffices)
  if (w == 0) {
    const short* Ab = &A_lds[NSTEP & 1][0];
    int m = lane >> 3, c8 = lane & 7;
    const short* hp = Ab + c8 * 256 + m * 8;
    float part = 0.0f;
#pragma unroll
    for (int qq = 0; qq < 4; ++qq) {
      bf16x8 hv = *(const bf16x8*)(hp + qq * 64);
#pragma unroll
      for (int e = 0; e < 8; ++e)
        part += bf2f(hv[e]) * Wy_lds[c8 * 32 + qq * 8 + e];
    }
    part += __shfl_xor(part, 1);
    part += __shfl_xor(part, 2);
    part += __shfl_xor(part, 4);
    if (c8 == 0) out[(wg * 8 + m) * 24 + 23] = part + byv;
  }
}

extern "C" void kernel_launch(void* const* d_in, const int* in_sizes, int n_in,
                              void* d_out, int out_size, void* d_ws, size_t ws_size,
                              hipStream_t stream) {
  const float* inputs0 = (const float*)d_in[0];
  const float* inputs1 = (const float*)d_in[1];
  const float* Wx      = (const float*)d_in[2];
  const float* Wh      = (const float*)d_in[3];
  const float* b       = (const float*)d_in[4];
  const float* Wy      = (const float*)d_in[5];
  const float* by      = (const float*)d_in[6];
  const float* dec_w   = (const float*)d_in[7];
  const float* dec_b   = (const float*)d_in[8];

  short* Wpack = (short*)d_ws;

  pack_kernel<<<dim3(432), dim3(64), 0, stream>>>(Wx, Wh, b, Wpack);
  lstm_kernel<<<dim3(256), dim3(512), 0, stream>>>(
      inputs0, inputs1, Wy, by, dec_w, dec_b, Wpack, (float*)d_out);
}